// Round 1
// baseline (391.392 us; speedup 1.0000x reference)
//
#include <hip/hip_runtime.h>

// Fused denorm + ReLU + AdaptiveAvgPool2d(56) for patch groups S=24,32,48.
// Reference: t = relu(x*std+mean); y = P_s @ t @ P_s^T  (P_s = [56,S] avg-pool matrix).
// Since S < 56, every output pixel averages a <=2x2 input window:
//   r0 = (i*S)/56, r1 = ceil((i+1)*S/56), window rows = r1-r0 in {1,2} (same for cols).
// One block per (patch, channel) map; input map staged in LDS with denorm+ReLU applied.

#define C_CH 256
#define OUTS 56
#define NPER 32

template<int S>
__device__ __forceinline__ void group_body(const float* __restrict__ x,
                                           const float* __restrict__ smean,
                                           const float* __restrict__ sstd,
                                           float* __restrict__ out,
                                           int local_bid, int n_base,
                                           float* __restrict__ lds) {
    const int n_local = local_bid >> 8;   // / 256 channels
    const int c       = local_bid & 255;
    const int n_glob  = n_base + n_local;
    const float mn = smean[n_glob * C_CH + c];
    const float sd = sstd [n_glob * C_CH + c];

    const float* xin = x + (size_t)(n_local * C_CH + c) * (S * S);
    const int tid = threadIdx.x;

    // Stage t = relu(x*sd + mn) into LDS. S*S is divisible by 4 for all S here.
    constexpr int NV = (S * S) / 4;
    const float4* x4 = (const float4*)xin;
    float4* l4 = (float4*)lds;
    for (int idx = tid; idx < NV; idx += 256) {
        float4 v = x4[idx];
        v.x = fmaxf(fmaf(v.x, sd, mn), 0.0f);
        v.y = fmaxf(fmaf(v.y, sd, mn), 0.0f);
        v.z = fmaxf(fmaf(v.z, sd, mn), 0.0f);
        v.w = fmaxf(fmaf(v.w, sd, mn), 0.0f);
        l4[idx] = v;
    }
    __syncthreads();

    float* outp = out + (size_t)(n_glob * C_CH + c) * (OUTS * OUTS);
    float4* out4 = (float4*)outp;

    // 56*56 = 3136 outputs = 784 float4 (56 % 4 == 0 -> float4 stays in one row).
    constexpr int NQ = (OUTS * OUTS) / 4;   // 784
    for (int q = tid; q < NQ; q += 256) {
        const int i  = q / (OUTS / 4);        // output row, divisor 14 (constant)
        const int j0 = (q % (OUTS / 4)) * 4;  // first output col of this float4
        const int r0 = (i * S) / OUTS;
        const int r1 = ((i + 1) * S + OUTS - 1) / OUTS;
        const int rc = r1 - r0;               // 1 or 2

        float o[4];
        #pragma unroll
        for (int k = 0; k < 4; ++k) {
            const int j  = j0 + k;
            const int c0 = (j * S) / OUTS;
            const int c1 = ((j + 1) * S + OUTS - 1) / OUTS;
            const int cc = c1 - c0;           // 1 or 2
            float acc = lds[r0 * S + c0];
            if (cc == 2) acc += lds[r0 * S + c0 + 1];
            if (rc == 2) {
                acc += lds[(r0 + 1) * S + c0];
                if (cc == 2) acc += lds[(r0 + 1) * S + c0 + 1];
            }
            // rc*cc in {1,2,4} -> reciprocal exact in fp32
            o[k] = acc * (1.0f / (float)(rc * cc));
        }
        float4 v; v.x = o[0]; v.y = o[1]; v.z = o[2]; v.w = o[3];
        out4[q] = v;
    }
}

__global__ __launch_bounds__(256) void PPIN_DC_20753281974843_kernel(
        const float* __restrict__ p24, const float* __restrict__ p32,
        const float* __restrict__ p48, const float* __restrict__ smean,
        const float* __restrict__ sstd, float* __restrict__ out) {
    __shared__ float lds[48 * 48];
    const int bid   = blockIdx.x;
    const int group = bid >> 13;      // 8192 blocks per group (32 patches * 256 ch)
    const int local = bid & 8191;
    if (group == 0)      group_body<24>(p24, smean, sstd, out, local, 0,        lds);
    else if (group == 1) group_body<32>(p32, smean, sstd, out, local, NPER,     lds);
    else                 group_body<48>(p48, smean, sstd, out, local, 2 * NPER, lds);
}

extern "C" void kernel_launch(void* const* d_in, const int* in_sizes, int n_in,
                              void* d_out, int out_size, void* d_ws, size_t ws_size,
                              hipStream_t stream) {
    const float* p24   = (const float*)d_in[0];
    const float* p32   = (const float*)d_in[1];
    const float* p48   = (const float*)d_in[2];
    const float* smean = (const float*)d_in[3];
    const float* sstd  = (const float*)d_in[4];
    float* out = (float*)d_out;

    // 3 groups * 32 patches * 256 channels = 24576 blocks, one (n,c) map each.
    PPIN_DC_20753281974843_kernel<<<dim3(24576), dim3(256), 0, stream>>>(
        p24, p32, p48, smean, sstd, out);
}